// Round 1
// baseline (14194.165 us; speedup 1.0000x reference)
//
#include <hip/hip_runtime.h>
#include <math.h>

typedef unsigned short u16;
typedef __bf16 bf16x8 __attribute__((ext_vector_type(8)));
typedef float f32x4 __attribute__((ext_vector_type(4)));

#define AS1(p) ((const __attribute__((address_space(1))) void*)(p))
#define AS3(p) ((__attribute__((address_space(3))) void*)(p))

__device__ __forceinline__ u16 f2bf(float x) {
  unsigned u = __float_as_uint(x);
  u = u + 0x7fffu + ((u >> 16) & 1u);
  return (u16)(u >> 16);
}
__device__ __forceinline__ float bflo(unsigned x){ return __uint_as_float(x << 16); }
__device__ __forceinline__ float bfhi(unsigned x){ return __uint_as_float(x & 0xffff0000u); }

// ---------------- generic f32 -> bf16 ----------------
__global__ __launch_bounds__(256) void f2bf_kernel(const float* __restrict__ in,
                                                   u16* __restrict__ out, int n) {
  int i = blockIdx.x * 256 + threadIdx.x;
  int stride = gridDim.x * 256;
  for (; i < n; i += stride) out[i] = f2bf(in[i]);
}

// ---------------- embedding gather -> bf16 ----------------
__global__ __launch_bounds__(256) void gather_kernel(const int* __restrict__ ids,
                                                     const float* __restrict__ embW,
                                                     u16* __restrict__ out) {
  int row = blockIdx.x;                       // token index b*1024+s
  long base = (long)ids[row] << 9;            // *512
  long obase = (long)row << 9;
  for (int c = threadIdx.x; c < 512; c += 256) out[obase + c] = f2bf(embW[base + c]);
}

// ---------------- bf16 MFMA GEMM: C[M,N] = A[M,K] @ Bt[N,K]^T (+bias[N]) ------
// m97-style: 128x128 tile, BK=32, 4 waves each 64x64, global_load_lds width 16.
__global__ __launch_bounds__(256) void gemm_bt(const u16* __restrict__ A,
                                               const u16* __restrict__ Bt,
                                               float* __restrict__ C,
                                               const float* __restrict__ bias,
                                               int M, int N, int K) {
  __shared__ __attribute__((aligned(16))) u16 lA[128 * 32];
  __shared__ __attribute__((aligned(16))) u16 lB[128 * 32];
  const int tid = threadIdx.x;
  const int w = tid >> 6, l = tid & 63;
  const int bn = blockIdx.x, bm = blockIdx.y;
  const int frow = l & 15, fq = l >> 4;
  const int wm = (w >> 1) * 64, wn = (w & 1) * 64;
  f32x4 acc[16];
#pragma unroll
  for (int i = 0; i < 16; i++) acc[i] = (f32x4){0.f, 0.f, 0.f, 0.f};

  const long a0 = (long)bm * 128 * K;
  const long b0 = (long)bn * 128 * K;
  for (int k0 = 0; k0 < K; k0 += 32) {
#pragma unroll
    for (int p = 0; p < 2; p++) {
      int q = (p * 4 + w) * 64 + l;          // chunk 0..511
      int r = q >> 2, c = (q & 3) << 3;      // row, col-offset (ushorts)
      __builtin_amdgcn_global_load_lds(AS1(A + a0 + (long)r * K + k0 + c),
                                       AS3(&lA[(p * 4 + w) * 512]), 16, 0, 0);
      __builtin_amdgcn_global_load_lds(AS1(Bt + b0 + (long)r * K + k0 + c),
                                       AS3(&lB[(p * 4 + w) * 512]), 16, 0, 0);
    }
    __syncthreads();
    bf16x8 af[4], bfv[4];
#pragma unroll
    for (int i = 0; i < 4; i++) af[i]  = *(const bf16x8*)&lA[(wm + i * 16 + frow) * 32 + fq * 8];
#pragma unroll
    for (int j = 0; j < 4; j++) bfv[j] = *(const bf16x8*)&lB[(wn + j * 16 + frow) * 32 + fq * 8];
#pragma unroll
    for (int i = 0; i < 4; i++)
#pragma unroll
      for (int j = 0; j < 4; j++)
        acc[i * 4 + j] = __builtin_amdgcn_mfma_f32_16x16x32_bf16(af[i], bfv[j], acc[i * 4 + j], 0, 0, 0);
    __syncthreads();
  }
  // C/D layout: col = lane&15, row = (lane>>4)*4 + reg  [verified m89/m91]
#pragma unroll
  for (int i = 0; i < 4; i++) {
    int row = bm * 128 + wm + i * 16 + fq * 4;
#pragma unroll
    for (int j = 0; j < 4; j++) {
      int col = bn * 128 + wn + j * 16 + frow;
      float bv = bias ? bias[col] : 0.f;
#pragma unroll
      for (int r = 0; r < 4; r++)
        C[(long)(row + r) * N + col] = acc[i * 4 + j][r] + bv;
    }
  }
}

// ---------------- GRU: persistent grid, per-step device barrier --------------
__device__ __forceinline__ void grid_barrier(unsigned* cnt, unsigned target) {
  __syncthreads();
  if (threadIdx.x == 0) {
    __threadfence();
    __hip_atomic_fetch_add(cnt, 1u, __ATOMIC_RELEASE, __HIP_MEMORY_SCOPE_AGENT);
    while (__hip_atomic_load(cnt, __ATOMIC_RELAXED, __HIP_MEMORY_SCOPE_AGENT) < target)
      __builtin_amdgcn_s_sleep(1);
    __threadfence();
  }
  __syncthreads();
}

// 128 WGs x 256 thr. WG g owns features f0=g*8..+8 -> W_hh rows {f, 1024+f, 2048+f}
// (24 rows x 1024 bf16 = 48 KB LDS). xproj already contains b_ih.
__global__ __launch_bounds__(256) void gru_kernel(const u16* __restrict__ Whh,
                                                  const float* __restrict__ b_hh,
                                                  const float* __restrict__ xproj,
                                                  float* __restrict__ hbuf,   // [2][2][1024] ping-pong
                                                  float* __restrict__ states, // [2][1024][1024]
                                                  unsigned* __restrict__ barcnt) {
  __shared__ __attribute__((aligned(16))) u16 lW[24 * 1024];
  __shared__ float hgs[2][24];
  const int g = blockIdx.x;
  const int tid = threadIdx.x;
  const int f0 = g * 8;
  // load weight slice: lr = gate*8+ff  ->  global row gate*1024 + f0+ff
  for (int c = tid; c < 3072; c += 256) {            // 3072 chunks of 8 ushorts
    int lr = c >> 7;
    int off = (c & 127) << 3;
    int gate = lr >> 3, ff = lr & 7;
    *(uint4*)&lW[(lr << 10) + off] =
        *(const uint4*)(Whh + ((long)(gate << 10) + f0 + ff) * 1024 + off);
  }
  if (tid < 16) { int b = tid >> 3, ff = tid & 7; hbuf[(b << 10) + f0 + ff] = 0.f; }
  unsigned bar = 1;
  grid_barrier(barcnt, bar * 128); bar++;

  const int w = tid >> 6, l = tid & 63;
  const int b = w >> 1, lr0 = (w & 1) * 12;
  for (int t = 0; t < 1024; t++) {
    const float* hc = hbuf + (((t & 1) << 1) + b) * 1024;
    float hreg[16];
    *(float4*)(hreg + 0)  = *(const float4*)(hc + (l << 3));
    *(float4*)(hreg + 4)  = *(const float4*)(hc + (l << 3) + 4);
    *(float4*)(hreg + 8)  = *(const float4*)(hc + 512 + (l << 3));
    *(float4*)(hreg + 12) = *(const float4*)(hc + 512 + (l << 3) + 4);
    for (int d = 0; d < 12; d++) {
      int lr = lr0 + d;
      const u16* wr = &lW[lr << 10];
      float s = 0.f;
#pragma unroll
      for (int u = 0; u < 2; u++) {
        uint4 wv = *(const uint4*)(wr + (u << 9) + (l << 3));
        const float* hh = hreg + (u << 3);
        s += hh[0] * bflo(wv.x) + hh[1] * bfhi(wv.x)
           + hh[2] * bflo(wv.y) + hh[3] * bfhi(wv.y)
           + hh[4] * bflo(wv.z) + hh[5] * bfhi(wv.z)
           + hh[6] * bflo(wv.w) + hh[7] * bfhi(wv.w);
      }
#pragma unroll
      for (int off = 32; off > 0; off >>= 1) s += __shfl_down(s, off, 64);
      if (l == 0) hgs[b][lr] = s + b_hh[((lr >> 3) << 10) + f0 + (lr & 7)];
    }
    __syncthreads();
    if (tid < 16) {
      int bb = tid >> 3, ff = tid & 7, f = f0 + ff;
      const float* xb = xproj + (long)((bb << 10) + t) * 3072;
      float hr = hgs[bb][ff], hz = hgs[bb][8 + ff], hn = hgs[bb][16 + ff];
      float r = 1.f / (1.f + expf(-(xb[f] + hr)));
      float z = 1.f / (1.f + expf(-(xb[1024 + f] + hz)));
      float n = tanhf(xb[2048 + f] + r * hn);
      float hp = hbuf[(((t & 1) << 1) + bb) * 1024 + f];
      float hnew = (1.f - z) * n + z * hp;
      hbuf[((((t + 1) & 1) << 1) + bb) * 1024 + f] = hnew;
      states[(long)((bb << 10) + t) * 1024 + f] = hnew;
    }
    grid_barrier(barcnt, bar * 128); bar++;
  }
}

// ---------------- mixed + RMSnorm + gate -------------------------------------
__global__ __launch_bounds__(256) void mix_kernel(const float* __restrict__ states,
                                                  const float* __restrict__ inres,
                                                  const float* __restrict__ gate_W,
                                                  const float* __restrict__ gate_b,
                                                  const float* __restrict__ rlam,
                                                  const float* __restrict__ ilam,
                                                  const float* __restrict__ mscale,
                                                  u16* __restrict__ mixed_bf,
                                                  float* __restrict__ gate6) {
  const int row = blockIdx.x, tid = threadIdx.x, w = tid >> 6, l = tid & 63;
  __shared__ float red[16];
  float rl = rlam[0], il = ilam[0];
  const float* sr = states + (long)row * 1024;
  const float* ir = inres + (long)row * 1024;
  float m[4]; float ss = 0.f;
#pragma unroll
  for (int u = 0; u < 4; u++) {
    int h = (u << 8) + tid;
    m[u] = rl * sr[h] + il * ir[h];
    ss += m[u] * m[u];
  }
#pragma unroll
  for (int off = 32; off > 0; off >>= 1) ss += __shfl_down(ss, off, 64);
  if (l == 0) red[w] = ss;
  __syncthreads();
  float tot = red[0] + red[1] + red[2] + red[3];
  float scale = rsqrtf(tot * (1.f / 1024.f) + 1.1920929e-07f);
  float gd = 0.f;
#pragma unroll
  for (int u = 0; u < 4; u++) {
    int h = (u << 8) + tid;
    float v = m[u] * scale;
    mixed_bf[(long)row * 1024 + h] = f2bf(v);
    gd += v * gate_W[h];
  }
#pragma unroll
  for (int off = 32; off > 0; off >>= 1) gd += __shfl_down(gd, off, 64);
  if (l == 0) red[8 + w] = gd;
  __syncthreads();
  if (tid == 0) {
    float gsum = red[8] + red[9] + red[10] + red[11] + gate_b[0];
    gate6[row] = (1.f / (1.f + expf(-gsum))) * mscale[0];
  }
}

// ---------------- strictly-causal softmax attention -> gated -----------------
__global__ __launch_bounds__(256) void attn_kernel(const float* __restrict__ q,
                                                   const float* __restrict__ k,
                                                   const float* __restrict__ gate6,
                                                   float* __restrict__ gated) {
  const int bi = blockIdx.x; const int b = bi >> 10, i = bi & 1023;
  if (i == 0) return;                      // row 0: no valid keys, contributes 0
  const int tid = threadIdx.x, w = tid >> 6, l = tid & 63;
  __shared__ float sc[1024];
  __shared__ float red[16];
  const float4 qv = *(const float4*)(q + (long)bi * 256 + (l << 2));
  for (int j = w; j < i; j += 4) {
    float4 kv = *(const float4*)(k + ((long)(b << 10) + j) * 256 + (l << 2));
    float s = qv.x * kv.x + qv.y * kv.y + qv.z * kv.z + qv.w * kv.w;
#pragma unroll
    for (int off = 32; off > 0; off >>= 1) s += __shfl_down(s, off, 64);
    if (l == 0) sc[j] = s * 0.0625f;       // 1/sqrt(256)
  }
  __syncthreads();
  float mx = -3.0e38f;
  for (int j = tid; j < i; j += 256) mx = fmaxf(mx, sc[j]);
#pragma unroll
  for (int off = 32; off > 0; off >>= 1) mx = fmaxf(mx, __shfl_down(mx, off, 64));
  if (l == 0) red[w] = mx;
  __syncthreads();
  mx = fmaxf(fmaxf(red[0], red[1]), fmaxf(red[2], red[3]));
  float sum = 0.f;
  for (int j = tid; j < i; j += 256) { float e = expf(sc[j] - mx); sc[j] = e; sum += e; }
#pragma unroll
  for (int off = 32; off > 0; off >>= 1) sum += __shfl_down(sum, off, 64);
  if (l == 0) red[8 + w] = sum;
  __syncthreads();
  sum = red[8] + red[9] + red[10] + red[11];
  float invs = gate6[bi] / sum;            // softmax*mask renorm == softmax over j<i
  float* grow = gated + (long)bi * 1024;
  for (int j = tid; j < i; j += 256) grow[j] = sc[j] * invs;
}

// ---------------- scatter-add into logits ------------------------------------
__global__ __launch_bounds__(256) void scatter_kernel(const int* __restrict__ ids,
                                                      const float* __restrict__ gated,
                                                      float* __restrict__ out) {
  const int bi = blockIdx.x; const int b = bi >> 10, i = bi & 1023;
  const float* g = gated + (long)bi * 1024;
  float* o = out + (long)bi * 32000;
  const int* idr = ids + (b << 10);
  for (int j = threadIdx.x; j < i; j += 256)
    atomicAdd(o + idr[j], g[j]);
}

extern "C" void kernel_launch(void* const* d_in, const int* in_sizes, int n_in,
                              void* d_out, int out_size, void* d_ws, size_t ws_size,
                              hipStream_t stream) {
  const int*   ids      = (const int*)  d_in[0];
  const float* emb_W    = (const float*)d_in[1];
  const float* W_ih     = (const float*)d_in[2];
  const float* W_hh     = (const float*)d_in[3];
  const float* b_ih     = (const float*)d_in[4];
  const float* b_hh     = (const float*)d_in[5];
  const float* in_res_W = (const float*)d_in[6];
  const float* q_W      = (const float*)d_in[7];
  const float* q_b      = (const float*)d_in[8];
  const float* k_W      = (const float*)d_in[9];
  const float* k_b      = (const float*)d_in[10];
  const float* gate_W   = (const float*)d_in[11];
  const float* gate_b   = (const float*)d_in[12];
  const float* h2e_W    = (const float*)d_in[13];
  const float* h2e_b    = (const float*)d_in[14];
  const float* out_bias = (const float*)d_in[15];
  const float* mscale   = (const float*)d_in[16];
  const float* rlam     = (const float*)d_in[17];
  const float* ilam     = (const float*)d_in[18];
  float* out = (float*)d_out;

  char* p = (char*)d_ws;
  auto alloc = [&](size_t b) { char* r = p; p += (b + 255) & ~(size_t)255; return (void*)r; };
  u16*   emb_bf   = (u16*)  alloc((size_t)2048 * 512 * 2);
  u16*   Wih_bf   = (u16*)  alloc((size_t)3072 * 512 * 2);
  u16*   inresW_bf= (u16*)  alloc((size_t)1024 * 512 * 2);
  u16*   Whh_bf   = (u16*)  alloc((size_t)3072 * 1024 * 2);
  u16*   h2e_bf   = (u16*)  alloc((size_t)512 * 1024 * 2);
  u16*   qW_bf    = (u16*)  alloc((size_t)256 * 1024 * 2);
  u16*   kW_bf    = (u16*)  alloc((size_t)256 * 1024 * 2);
  u16*   embW_bf  = (u16*)  alloc((size_t)32000 * 512 * 2);
  float* xproj    = (float*)alloc((size_t)2048 * 3072 * 4);
  float* inres    = (float*)alloc((size_t)2048 * 1024 * 4);
  float* states   = (float*)alloc((size_t)2048 * 1024 * 4);
  u16*   mixed_bf = (u16*)  alloc((size_t)2048 * 1024 * 2);
  float* tbuf     = (float*)alloc((size_t)2048 * 512 * 4);
  u16*   t_bf     = (u16*)  alloc((size_t)2048 * 512 * 2);
  float* qbuf     = (float*)alloc((size_t)2048 * 256 * 4);
  float* kbuf     = (float*)alloc((size_t)2048 * 256 * 4);
  float* gated    = (float*)alloc((size_t)2048 * 1024 * 4);
  float* gate6    = (float*)alloc((size_t)2048 * 4);
  float* hbuf     = (float*)alloc((size_t)4 * 1024 * 4);
  unsigned* barcnt= (unsigned*)alloc(256);

  // weight / input conversions to bf16
  f2bf_kernel<<<1024, 256, 0, stream>>>(W_ih, Wih_bf, 3072 * 512);
  f2bf_kernel<<<512, 256, 0, stream>>>(in_res_W, inresW_bf, 1024 * 512);
  f2bf_kernel<<<1024, 256, 0, stream>>>(W_hh, Whh_bf, 3072 * 1024);
  f2bf_kernel<<<512, 256, 0, stream>>>(h2e_W, h2e_bf, 512 * 1024);
  f2bf_kernel<<<256, 256, 0, stream>>>(q_W, qW_bf, 256 * 1024);
  f2bf_kernel<<<256, 256, 0, stream>>>(k_W, kW_bf, 256 * 1024);
  f2bf_kernel<<<2048, 256, 0, stream>>>(emb_W, embW_bf, 32000 * 512);
  gather_kernel<<<2048, 256, 0, stream>>>(ids, emb_W, emb_bf);

  // x_proj = emb @ W_ih.T + b_ih ;  inres = emb @ in_res_W.T
  gemm_bt<<<dim3(24, 16), 256, 0, stream>>>(emb_bf, Wih_bf, xproj, b_ih, 2048, 3072, 512);
  gemm_bt<<<dim3(8, 16), 256, 0, stream>>>(emb_bf, inresW_bf, inres, nullptr, 2048, 1024, 512);

  // sequential GRU over S=1024 (persistent grid + per-step device barrier)
  hipMemsetAsync(barcnt, 0, 256, stream);
  gru_kernel<<<128, 256, 0, stream>>>(Whh_bf, b_hh, xproj, hbuf, states, barcnt);

  // mixed + RMS + gate
  mix_kernel<<<2048, 256, 0, stream>>>(states, inres, gate_W, gate_b, rlam, ilam, mscale,
                                       mixed_bf, gate6);

  // q, k, t projections
  gemm_bt<<<dim3(2, 16), 256, 0, stream>>>(mixed_bf, qW_bf, qbuf, q_b, 2048, 256, 1024);
  gemm_bt<<<dim3(2, 16), 256, 0, stream>>>(mixed_bf, kW_bf, kbuf, k_b, 2048, 256, 1024);
  gemm_bt<<<dim3(4, 16), 256, 0, stream>>>(mixed_bf, h2e_bf, tbuf, h2e_b, 2048, 512, 1024);
  f2bf_kernel<<<512, 256, 0, stream>>>(tbuf, t_bf, 2048 * 512);

  // attention -> gated
  attn_kernel<<<2048, 256, 0, stream>>>(qbuf, kbuf, gate6, gated);

  // base logits (big GEMM, writes all of d_out) then scatter-add
  gemm_bt<<<dim3(250, 16), 256, 0, stream>>>(t_bf, embW_bf, out, out_bias, 2048, 32000, 512);
  scatter_kernel<<<2048, 256, 0, stream>>>(ids, gated, out);
}

// Round 2
// 5782.079 us; speedup vs baseline: 2.4549x; 2.4549x over previous
//
#include <hip/hip_runtime.h>
#include <math.h>

typedef unsigned short u16;
typedef unsigned long long u64;
typedef __bf16 bf16x8 __attribute__((ext_vector_type(8)));
typedef float f32x4 __attribute__((ext_vector_type(4)));

#define AS1(p) ((const __attribute__((address_space(1))) void*)(p))
#define AS3(p) ((__attribute__((address_space(3))) void*)(p))

__device__ __forceinline__ u16 f2bf(float x) {
  unsigned u = __float_as_uint(x);
  u = u + 0x7fffu + ((u >> 16) & 1u);
  return (u16)(u >> 16);
}
__device__ __forceinline__ float bflo(unsigned x){ return __uint_as_float(x << 16); }
__device__ __forceinline__ float bfhi(unsigned x){ return __uint_as_float(x & 0xffff0000u); }

// ---------------- generic f32 -> bf16 ----------------
__global__ __launch_bounds__(256) void f2bf_kernel(const float* __restrict__ in,
                                                   u16* __restrict__ out, int n) {
  int i = blockIdx.x * 256 + threadIdx.x;
  int stride = gridDim.x * 256;
  for (; i < n; i += stride) out[i] = f2bf(in[i]);
}

// ---------------- embedding gather -> bf16 ----------------
__global__ __launch_bounds__(256) void gather_kernel(const int* __restrict__ ids,
                                                     const float* __restrict__ embW,
                                                     u16* __restrict__ out) {
  int row = blockIdx.x;                       // token index b*1024+s
  long base = (long)ids[row] << 9;            // *512
  long obase = (long)row << 9;
  for (int c = threadIdx.x; c < 512; c += 256) out[obase + c] = f2bf(embW[base + c]);
}

// ---------------- bf16 MFMA GEMM: C[M,N] = A[M,K] @ Bt[N,K]^T (+bias[N]) ------
__global__ __launch_bounds__(256) void gemm_bt(const u16* __restrict__ A,
                                               const u16* __restrict__ Bt,
                                               float* __restrict__ C,
                                               const float* __restrict__ bias,
                                               int M, int N, int K) {
  __shared__ __attribute__((aligned(16))) u16 lA[128 * 32];
  __shared__ __attribute__((aligned(16))) u16 lB[128 * 32];
  const int tid = threadIdx.x;
  const int w = tid >> 6, l = tid & 63;
  const int bn = blockIdx.x, bm = blockIdx.y;
  const int frow = l & 15, fq = l >> 4;
  const int wm = (w >> 1) * 64, wn = (w & 1) * 64;
  f32x4 acc[16];
#pragma unroll
  for (int i = 0; i < 16; i++) acc[i] = (f32x4){0.f, 0.f, 0.f, 0.f};

  const long a0 = (long)bm * 128 * K;
  const long b0 = (long)bn * 128 * K;
  for (int k0 = 0; k0 < K; k0 += 32) {
#pragma unroll
    for (int p = 0; p < 2; p++) {
      int q = (p * 4 + w) * 64 + l;          // chunk 0..511
      int r = q >> 2, c = (q & 3) << 3;      // row, col-offset (ushorts)
      __builtin_amdgcn_global_load_lds(AS1(A + a0 + (long)r * K + k0 + c),
                                       AS3(&lA[(p * 4 + w) * 512]), 16, 0, 0);
      __builtin_amdgcn_global_load_lds(AS1(Bt + b0 + (long)r * K + k0 + c),
                                       AS3(&lB[(p * 4 + w) * 512]), 16, 0, 0);
    }
    __syncthreads();
    bf16x8 af[4], bfv[4];
#pragma unroll
    for (int i = 0; i < 4; i++) af[i]  = *(const bf16x8*)&lA[(wm + i * 16 + frow) * 32 + fq * 8];
#pragma unroll
    for (int j = 0; j < 4; j++) bfv[j] = *(const bf16x8*)&lB[(wn + j * 16 + frow) * 32 + fq * 8];
#pragma unroll
    for (int i = 0; i < 4; i++)
#pragma unroll
      for (int j = 0; j < 4; j++)
        acc[i * 4 + j] = __builtin_amdgcn_mfma_f32_16x16x32_bf16(af[i], bfv[j], acc[i * 4 + j], 0, 0, 0);
    __syncthreads();
  }
#pragma unroll
  for (int i = 0; i < 4; i++) {
    int row = bm * 128 + wm + i * 16 + fq * 4;
#pragma unroll
    for (int j = 0; j < 4; j++) {
      int col = bn * 128 + wn + j * 16 + frow;
      float bv = bias ? bias[col] : 0.f;
#pragma unroll
      for (int r = 0; r < 4; r++)
        C[(long)(row + r) * N + col] = acc[i * 4 + j][r] + bv;
    }
  }
}

// ---------------- GRU: persistent grid, fence-free device barrier ------------
// All cross-WG data (h) moves via agent-scope coherent loads/stores (bypass the
// non-coherent per-XCD L1/L2, hit the Infinity Cache coherence point). The
// barrier counter is fully relaxed; ordering comes from s_waitcnt vmcnt(0) in
// wave 0, which issued both the h-stores and the counter add. NO __threadfence
// -> no buffer_wbl2 / buffer_inv L2 flushes per step.
__device__ __forceinline__ void gbar(unsigned* cnt, unsigned target) {
  __syncthreads();
  if (threadIdx.x == 0) {
    __builtin_amdgcn_s_waitcnt(0);   // drain wave-0 stores (h + states) to coherence point
    __hip_atomic_fetch_add(cnt, 1u, __ATOMIC_RELAXED, __HIP_MEMORY_SCOPE_AGENT);
    while (__hip_atomic_load(cnt, __ATOMIC_RELAXED, __HIP_MEMORY_SCOPE_AGENT) < target)
      __builtin_amdgcn_s_sleep(1);
  }
  __syncthreads();
}

// 128 WGs x 256 thr. WG g owns features f0=g*8..+8 -> W_hh rows {f, 1024+f, 2048+f}
// lW row stride padded to 1032 u16 (2064 B -> 12-bank rotation per row-group).
// h communicated as bf16 (hbuf: [2 parity][2 batch][1024] u16, pre-zeroed).
__global__ __launch_bounds__(256) void gru_kernel(const u16* __restrict__ Whh,
                                                  const float* __restrict__ b_hh,
                                                  const float* __restrict__ xproj,
                                                  u16* __restrict__ hbuf,
                                                  float* __restrict__ states, // [2][1024][1024]
                                                  unsigned* __restrict__ barcnt) {
  __shared__ __attribute__((aligned(16))) u16 lW[24 * 1032];
  __shared__ float hgs[2][24];
  const int g = blockIdx.x;
  const int tid = threadIdx.x;
  const int f0 = g * 8;
  for (int c = tid; c < 3072; c += 256) {            // 3072 chunks of 8 ushorts
    int lr = c >> 7, off = (c & 127) << 3;
    int gate = lr >> 3, ff = lr & 7;
    *(uint4*)(lW + lr * 1032 + off) =
        *(const uint4*)(Whh + ((long)(gate << 10) + f0 + ff) * 1024 + off);
  }
  __syncthreads();

  const int w = tid >> 6, l = tid & 63;
  const int b = w >> 1, lr0 = (w & 1) * 12;
  const int g16 = l >> 4, lane16 = l & 15;
  float hp = 0.f;                                    // fp32 h owned by tid<16

  for (int t = 0; t < 1024; t++) {
    // prefetch x-gates (independent of h; in flight during the dots)
    float xr = 0.f, xz = 0.f, xn = 0.f;
    if (tid < 16) {
      int bb = tid >> 3, ff = tid & 7;
      const float* xb = xproj + (long)((bb << 10) + t) * 3072 + f0 + ff;
      xr = xb[0]; xz = xb[1024]; xn = xb[2048];
    }
    // coherent h load: lane covers cols {128u + 8*lane16 .. +7}, u=0..7
    const u64* h64 = (const u64*)(hbuf + ((t & 1) << 11) + (b << 10));
    u64 qa[8], qb[8];
#pragma unroll
    for (int u = 0; u < 8; u++) {
      qa[u] = __hip_atomic_load(h64 + (u << 5) + (lane16 << 1),     __ATOMIC_RELAXED, __HIP_MEMORY_SCOPE_AGENT);
      qb[u] = __hip_atomic_load(h64 + (u << 5) + (lane16 << 1) + 1, __ATOMIC_RELAXED, __HIP_MEMORY_SCOPE_AGENT);
    }
    float hv[64];
#pragma unroll
    for (int u = 0; u < 8; u++) {
      unsigned a0 = (unsigned)qa[u], a1 = (unsigned)(qa[u] >> 32);
      unsigned b0v = (unsigned)qb[u], b1 = (unsigned)(qb[u] >> 32);
      hv[u*8+0]=bflo(a0); hv[u*8+1]=bfhi(a0); hv[u*8+2]=bflo(a1); hv[u*8+3]=bfhi(a1);
      hv[u*8+4]=bflo(b0v); hv[u*8+5]=bfhi(b0v); hv[u*8+6]=bflo(b1); hv[u*8+7]=bfhi(b1);
    }
    // each 16-lane group handles 3 rows; 4-level shfl reduce (12 shfls/step)
#pragma unroll
    for (int r = 0; r < 3; r++) {
      int lr = lr0 + g16 * 3 + r;
      const u16* wr = lW + lr * 1032 + (lane16 << 3);
      float s = 0.f;
#pragma unroll
      for (int u = 0; u < 8; u++) {
        uint4 wv = *(const uint4*)(wr + (u << 7));
        s += hv[u*8+0]*bflo(wv.x) + hv[u*8+1]*bfhi(wv.x)
           + hv[u*8+2]*bflo(wv.y) + hv[u*8+3]*bfhi(wv.y)
           + hv[u*8+4]*bflo(wv.z) + hv[u*8+5]*bfhi(wv.z)
           + hv[u*8+6]*bflo(wv.w) + hv[u*8+7]*bfhi(wv.w);
      }
      s += __shfl_down(s, 8, 64);
      s += __shfl_down(s, 4, 64);
      s += __shfl_down(s, 2, 64);
      s += __shfl_down(s, 1, 64);
      if (lane16 == 0) hgs[b][lr] = s + b_hh[((lr >> 3) << 10) + f0 + (lr & 7)];
    }
    __syncthreads();
    if (tid < 16) {
      int bb = tid >> 3, ff = tid & 7, f = f0 + ff;
      float rr = 1.f / (1.f + expf(-(xr + hgs[bb][ff])));
      float zz = 1.f / (1.f + expf(-(xz + hgs[bb][8 + ff])));
      float nn = tanhf(xn + rr * hgs[bb][16 + ff]);
      float hnew = (1.f - zz) * nn + zz * hp;
      hp = hnew;
      states[(long)((bb << 10) + t) * 1024 + f] = hnew;
      __hip_atomic_store(hbuf + (((t + 1) & 1) << 11) + (bb << 10) + f, f2bf(hnew),
                         __ATOMIC_RELAXED, __HIP_MEMORY_SCOPE_AGENT);
    }
    gbar(barcnt, (t + 1) * 128u);
  }
}

// ---------------- mixed + RMSnorm + gate -------------------------------------
__global__ __launch_bounds__(256) void mix_kernel(const float* __restrict__ states,
                                                  const float* __restrict__ inres,
                                                  const float* __restrict__ gate_W,
                                                  const float* __restrict__ gate_b,
                                                  const float* __restrict__ rlam,
                                                  const float* __restrict__ ilam,
                                                  const float* __restrict__ mscale,
                                                  u16* __restrict__ mixed_bf,
                                                  float* __restrict__ gate6) {
  const int row = blockIdx.x, tid = threadIdx.x, w = tid >> 6, l = tid & 63;
  __shared__ float red[16];
  float rl = rlam[0], il = ilam[0];
  const float* sr = states + (long)row * 1024;
  const float* ir = inres + (long)row * 1024;
  float m[4]; float ss = 0.f;
#pragma unroll
  for (int u = 0; u < 4; u++) {
    int h = (u << 8) + tid;
    m[u] = rl * sr[h] + il * ir[h];
    ss += m[u] * m[u];
  }
#pragma unroll
  for (int off = 32; off > 0; off >>= 1) ss += __shfl_down(ss, off, 64);
  if (l == 0) red[w] = ss;
  __syncthreads();
  float tot = red[0] + red[1] + red[2] + red[3];
  float scale = rsqrtf(tot * (1.f / 1024.f) + 1.1920929e-07f);
  float gd = 0.f;
#pragma unroll
  for (int u = 0; u < 4; u++) {
    int h = (u << 8) + tid;
    float v = m[u] * scale;
    mixed_bf[(long)row * 1024 + h] = f2bf(v);
    gd += v * gate_W[h];
  }
#pragma unroll
  for (int off = 32; off > 0; off >>= 1) gd += __shfl_down(gd, off, 64);
  if (l == 0) red[8 + w] = gd;
  __syncthreads();
  if (tid == 0) {
    float gsum = red[8] + red[9] + red[10] + red[11] + gate_b[0];
    gate6[row] = (1.f / (1.f + expf(-gsum))) * mscale[0];
  }
}

// ---------------- strictly-causal softmax attention -> gated -----------------
__global__ __launch_bounds__(256) void attn_kernel(const float* __restrict__ q,
                                                   const float* __restrict__ k,
                                                   const float* __restrict__ gate6,
                                                   float* __restrict__ gated) {
  const int bi = blockIdx.x; const int b = bi >> 10, i = bi & 1023;
  if (i == 0) return;
  const int tid = threadIdx.x, w = tid >> 6, l = tid & 63;
  __shared__ float sc[1024];
  __shared__ float red[16];
  const float4 qv = *(const float4*)(q + (long)bi * 256 + (l << 2));
  for (int j = w; j < i; j += 4) {
    float4 kv = *(const float4*)(k + ((long)(b << 10) + j) * 256 + (l << 2));
    float s = qv.x * kv.x + qv.y * kv.y + qv.z * kv.z + qv.w * kv.w;
#pragma unroll
    for (int off = 32; off > 0; off >>= 1) s += __shfl_down(s, off, 64);
    if (l == 0) sc[j] = s * 0.0625f;       // 1/sqrt(256)
  }
  __syncthreads();
  float mx = -3.0e38f;
  for (int j = tid; j < i; j += 256) mx = fmaxf(mx, sc[j]);
#pragma unroll
  for (int off = 32; off > 0; off >>= 1) mx = fmaxf(mx, __shfl_down(mx, off, 64));
  if (l == 0) red[w] = mx;
  __syncthreads();
  mx = fmaxf(fmaxf(red[0], red[1]), fmaxf(red[2], red[3]));
  float sum = 0.f;
  for (int j = tid; j < i; j += 256) { float e = expf(sc[j] - mx); sc[j] = e; sum += e; }
#pragma unroll
  for (int off = 32; off > 0; off >>= 1) sum += __shfl_down(sum, off, 64);
  if (l == 0) red[8 + w] = sum;
  __syncthreads();
  sum = red[8] + red[9] + red[10] + red[11];
  float invs = gate6[bi] / sum;
  float* grow = gated + (long)bi * 1024;
  for (int j = tid; j < i; j += 256) grow[j] = sc[j] * invs;
}

// ---------------- scatter-add into logits ------------------------------------
__global__ __launch_bounds__(256) void scatter_kernel(const int* __restrict__ ids,
                                                      const float* __restrict__ gated,
                                                      float* __restrict__ out) {
  const int bi = blockIdx.x; const int b = bi >> 10, i = bi & 1023;
  const float* g = gated + (long)bi * 1024;
  float* o = out + (long)bi * 32000;
  const int* idr = ids + (b << 10);
  for (int j = threadIdx.x; j < i; j += 256)
    atomicAdd(o + idr[j], g[j]);
}

extern "C" void kernel_launch(void* const* d_in, const int* in_sizes, int n_in,
                              void* d_out, int out_size, void* d_ws, size_t ws_size,
                              hipStream_t stream) {
  const int*   ids      = (const int*)  d_in[0];
  const float* emb_W    = (const float*)d_in[1];
  const float* W_ih     = (const float*)d_in[2];
  const float* W_hh     = (const float*)d_in[3];
  const float* b_ih     = (const float*)d_in[4];
  const float* b_hh     = (const float*)d_in[5];
  const float* in_res_W = (const float*)d_in[6];
  const float* q_W      = (const float*)d_in[7];
  const float* q_b      = (const float*)d_in[8];
  const float* k_W      = (const float*)d_in[9];
  const float* k_b      = (const float*)d_in[10];
  const float* gate_W   = (const float*)d_in[11];
  const float* gate_b   = (const float*)d_in[12];
  const float* h2e_W    = (const float*)d_in[13];
  const float* h2e_b    = (const float*)d_in[14];
  const float* out_bias = (const float*)d_in[15];
  const float* mscale   = (const float*)d_in[16];
  const float* rlam     = (const float*)d_in[17];
  const float* ilam     = (const float*)d_in[18];
  float* out = (float*)d_out;

  char* p = (char*)d_ws;
  auto alloc = [&](size_t b) { char* r = p; p += (b + 255) & ~(size_t)255; return (void*)r; };
  u16*   emb_bf   = (u16*)  alloc((size_t)2048 * 512 * 2);
  u16*   Wih_bf   = (u16*)  alloc((size_t)3072 * 512 * 2);
  u16*   inresW_bf= (u16*)  alloc((size_t)1024 * 512 * 2);
  u16*   Whh_bf   = (u16*)  alloc((size_t)3072 * 1024 * 2);
  u16*   h2e_bf   = (u16*)  alloc((size_t)512 * 1024 * 2);
  u16*   qW_bf    = (u16*)  alloc((size_t)256 * 1024 * 2);
  u16*   kW_bf    = (u16*)  alloc((size_t)256 * 1024 * 2);
  u16*   embW_bf  = (u16*)  alloc((size_t)32000 * 512 * 2);
  float* xproj    = (float*)alloc((size_t)2048 * 3072 * 4);
  float* inres    = (float*)alloc((size_t)2048 * 1024 * 4);
  float* states   = (float*)alloc((size_t)2048 * 1024 * 4);
  u16*   mixed_bf = (u16*)  alloc((size_t)2048 * 1024 * 2);
  float* tbuf     = (float*)alloc((size_t)2048 * 512 * 4);
  u16*   t_bf     = (u16*)  alloc((size_t)2048 * 512 * 2);
  float* qbuf     = (float*)alloc((size_t)2048 * 256 * 4);
  float* kbuf     = (float*)alloc((size_t)2048 * 256 * 4);
  float* gated    = (float*)alloc((size_t)2048 * 1024 * 4);
  float* gate6    = (float*)alloc((size_t)2048 * 4);
  u16*   hbuf     = (u16*)  alloc((size_t)2 * 2 * 1024 * 2);
  unsigned* barcnt= (unsigned*)alloc(256);

  hipMemsetAsync(hbuf, 0, 2 * 2 * 1024 * 2, stream);
  hipMemsetAsync(barcnt, 0, 256, stream);

  // weight / input conversions to bf16
  f2bf_kernel<<<1024, 256, 0, stream>>>(W_ih, Wih_bf, 3072 * 512);
  f2bf_kernel<<<512, 256, 0, stream>>>(in_res_W, inresW_bf, 1024 * 512);
  f2bf_kernel<<<1024, 256, 0, stream>>>(W_hh, Whh_bf, 3072 * 1024);
  f2bf_kernel<<<512, 256, 0, stream>>>(h2e_W, h2e_bf, 512 * 1024);
  f2bf_kernel<<<256, 256, 0, stream>>>(q_W, qW_bf, 256 * 1024);
  f2bf_kernel<<<256, 256, 0, stream>>>(k_W, kW_bf, 256 * 1024);
  f2bf_kernel<<<2048, 256, 0, stream>>>(emb_W, embW_bf, 32000 * 512);
  gather_kernel<<<2048, 256, 0, stream>>>(ids, emb_W, emb_bf);

  // x_proj = emb @ W_ih.T + b_ih ;  inres = emb @ in_res_W.T
  gemm_bt<<<dim3(24, 16), 256, 0, stream>>>(emb_bf, Wih_bf, xproj, b_ih, 2048, 3072, 512);
  gemm_bt<<<dim3(8, 16), 256, 0, stream>>>(emb_bf, inresW_bf, inres, nullptr, 2048, 1024, 512);

  // sequential GRU over S=1024 (persistent grid + fence-free device barrier)
  gru_kernel<<<128, 256, 0, stream>>>(Whh_bf, b_hh, xproj, hbuf, states, barcnt);

  // mixed + RMS + gate
  mix_kernel<<<2048, 256, 0, stream>>>(states, inres, gate_W, gate_b, rlam, ilam, mscale,
                                       mixed_bf, gate6);

  // q, k, t projections
  gemm_bt<<<dim3(2, 16), 256, 0, stream>>>(mixed_bf, qW_bf, qbuf, q_b, 2048, 256, 1024);
  gemm_bt<<<dim3(2, 16), 256, 0, stream>>>(mixed_bf, kW_bf, kbuf, k_b, 2048, 256, 1024);
  gemm_bt<<<dim3(4, 16), 256, 0, stream>>>(mixed_bf, h2e_bf, tbuf, h2e_b, 2048, 512, 1024);
  f2bf_kernel<<<512, 256, 0, stream>>>(tbuf, t_bf, 2048 * 512);

  // attention -> gated
  attn_kernel<<<2048, 256, 0, stream>>>(qbuf, kbuf, gate6, gated);

  // base logits (big GEMM, writes all of d_out) then scatter-add
  gemm_bt<<<dim3(250, 16), 256, 0, stream>>>(t_bf, embW_bf, out, out_bias, 2048, 32000, 512);
  scatter_kernel<<<2048, 256, 0, stream>>>(ids, gated, out);
}